// Round 6
// baseline (422.599 us; speedup 1.0000x reference)
//
#include <hip/hip_runtime.h>
#include <math.h>

// SpatialAttention: x[16,224,224,256] f32 (NHWC)
//   max/mean over C -> [B,H,W,2] -> conv7x7(2->1, SAME) -> sigmoid -> x * attn
//
// Pipelined multi-dispatch: dispatch K_b = mul(image b-1) + pool(image b).
// Dispatch boundary = CP-level device barrier; mul's x re-read hits Infinity
// Cache (one image = 50 MB << 256 MB; proven R4: FETCH == x once).
// R6: uniform blocks — every block grid-strides over BOTH roles, so all 2048
// blocks (8/CU exactly) carry identical work; no role imbalance, no tail.
#define B_ 16
#define H_ 224
#define W_ 224
#define C_ 256
#define IMGPIX (H_*W_)      // 50176
#define NBLK 2048           // 8 blocks/CU * 256 CU; 32 waves/CU
#define NWAVE (NBLK*4)      // 8192
#define NGRP  (NBLK*16)     // 32768 16-lane groups

typedef float f32x4 __attribute__((ext_vector_type(4)));

__global__ __launch_bounds__(256) void step_kernel(const float* __restrict__ x,
                                                   const float* __restrict__ cw,   // [7,7,2,1]
                                                   const float* __restrict__ cb,
                                                   float* __restrict__ out,
                                                   float2* __restrict__ pooled,
                                                   int mb, int pb) {
    const int t    = threadIdx.x;
    const int lane = t & 63;

    // ---------- role 1: conv7x7 + sigmoid + scale for image mb ----------
    if (mb >= 0) {
        float wm = 0.0f, wa = 0.0f;
        if (lane < 49) { wm = cw[lane * 2]; wa = cw[lane * 2 + 1]; }
        const float bias = cb[0];
        const int kh = lane / 7 - 3;
        const int kw = lane % 7 - 3;
        const float*  xb = x   + (size_t)mb * IMGPIX * C_;
        float*        ob = out + (size_t)mb * IMGPIX * C_;
        const float2* pbase = pooled + (size_t)mb * IMGPIX;
        const int gw = blockIdx.x * 4 + (t >> 6);          // 0..8191

        for (int px = gw; px < IMGPIX; px += NWAVE) {
            const int h = px / W_, w = px % W_;
            float acc = 0.0f;
            if (lane < 49) {
                const int hh = h + kh, ww = w + kw;
                if (hh >= 0 && hh < H_ && ww >= 0 && ww < W_) {
                    const float2 pv = pbase[hh * W_ + ww];
                    acc = fmaf(pv.x, wm, pv.y * wa);
                }
            }
            #pragma unroll
            for (int off = 1; off < 64; off <<= 1) acc += __shfl_xor(acc, off);
            const float attn = 1.0f / (1.0f + expf(-(acc + bias)));

            f32x4 v = ((const f32x4*)(xb + (size_t)px * C_))[lane];   // L3 hit
            v.x *= attn; v.y *= attn; v.z *= attn; v.w *= attn;
            __builtin_nontemporal_store(v, &((f32x4*)ob)[(size_t)px * 64 + lane]);
        }
    }

    // ---------- role 2: channel max/mean pool for image pb ----------
    if (pb >= 0) {
        const int gg  = blockIdx.x * 16 + (t >> 4);        // 0..32767
        const int sub = t & 15;
        const float* xb  = x + (size_t)pb * IMGPIX * C_;
        float2*      pot = pooled + (size_t)pb * IMGPIX;

        for (int px = gg; px < IMGPIX; px += NGRP) {
            const f32x4* p4 = (const f32x4*)(xb + (size_t)px * C_);
            float m = -INFINITY, s = 0.0f;
            #pragma unroll
            for (int j = 0; j < 4; ++j) {
                f32x4 v = p4[j * 16 + sub];                // normal load: allocate in L3
                m = fmaxf(m, fmaxf(fmaxf(v.x, v.y), fmaxf(v.z, v.w)));
                s += (v.x + v.y) + (v.z + v.w);
            }
            #pragma unroll
            for (int off = 1; off < 16; off <<= 1) {
                m = fmaxf(m, __shfl_xor(m, off));
                s += __shfl_xor(s, off);
            }
            if (sub == 0) pot[px] = make_float2(m, s * (1.0f / 256.0f));
        }
    }
}

extern "C" void kernel_launch(void* const* d_in, const int* in_sizes, int n_in,
                              void* d_out, int out_size, void* d_ws, size_t ws_size,
                              hipStream_t stream) {
    const float* x  = (const float*)d_in[0];
    const float* cw = (const float*)d_in[1];
    const float* cb = (const float*)d_in[2];
    float* out      = (float*)d_out;
    float2* pooled  = (float2*)d_ws;        // 16*50176*8 B = 6.4 MB

    for (int d = 0; d <= B_; ++d) {
        const int mb = d - 1;                  // mul image (-1 = none)
        const int pb = (d < B_) ? d : -1;      // pool image (-1 = none)
        step_kernel<<<NBLK, 256, 0, stream>>>(x, cw, cb, out, pooled, mb, pb);
    }
}

// Round 7
// 417.710 us; speedup vs baseline: 1.0117x; 1.0117x over previous
//
#include <hip/hip_runtime.h>
#include <math.h>

// SpatialAttention: x[16,224,224,256] f32 (NHWC)
//   max/mean over C -> [B,H,W,2] -> conv7x7(2->1, SAME) -> sigmoid -> x * attn
//
// Pipelined multi-dispatch, 2 images per step (9 dispatches):
//   dispatch d = mul(images 2d-2,2d-1) + pool(images 2d,2d+1).
// Dispatch boundary = CP-level device barrier; mul's x re-read is served by
// Infinity Cache (window: 100 MB pooled + 100 MB retained < 256 MB; out
// writes are nontemporal and should not allocate).
// A/B vs R6 (17 dispatches): tests per-dispatch-overhead vs fabric-bound.
#define B_ 16
#define H_ 224
#define W_ 224
#define C_ 256
#define IMGPIX (H_*W_)      // 50176
#define NBLK 2048           // 8 blocks/CU * 256 CU; 32 waves/CU
#define NWAVE (NBLK*4)      // 8192
#define NGRP  (NBLK*16)     // 32768 16-lane groups

typedef float f32x4 __attribute__((ext_vector_type(4)));

__global__ __launch_bounds__(256) void step_kernel(const float* __restrict__ x,
                                                   const float* __restrict__ cw,   // [7,7,2,1]
                                                   const float* __restrict__ cb,
                                                   float* __restrict__ out,
                                                   float2* __restrict__ pooled,
                                                   int mb0, int pb0) {
    const int t    = threadIdx.x;
    const int lane = t & 63;

    // ---------- role 1: conv7x7 + sigmoid + scale for images mb0, mb0+1 ----------
    if (mb0 >= 0) {
        float wm = 0.0f, wa = 0.0f;
        if (lane < 49) { wm = cw[lane * 2]; wa = cw[lane * 2 + 1]; }
        const float bias = cb[0];
        const int kh = lane / 7 - 3;
        const int kw = lane % 7 - 3;
        const int gw = blockIdx.x * 4 + (t >> 6);          // 0..8191

        for (int q = gw; q < 2 * IMGPIX; q += NWAVE) {
            const int img = q / IMGPIX;                    // 0 or 1
            const int px  = q - img * IMGPIX;
            const int b   = mb0 + img;
            const float*  xb    = x   + (size_t)b * IMGPIX * C_;
            float*        ob    = out + (size_t)b * IMGPIX * C_;
            const float2* pbase = pooled + (size_t)b * IMGPIX;

            const int h = px / W_, w = px % W_;
            float acc = 0.0f;
            if (lane < 49) {
                const int hh = h + kh, ww = w + kw;
                if (hh >= 0 && hh < H_ && ww >= 0 && ww < W_) {
                    const float2 pv = pbase[hh * W_ + ww];
                    acc = fmaf(pv.x, wm, pv.y * wa);
                }
            }
            #pragma unroll
            for (int off = 1; off < 64; off <<= 1) acc += __shfl_xor(acc, off);
            const float attn = 1.0f / (1.0f + expf(-(acc + bias)));

            f32x4 v = ((const f32x4*)(xb + (size_t)px * C_))[lane];   // L3 hit
            v.x *= attn; v.y *= attn; v.z *= attn; v.w *= attn;
            __builtin_nontemporal_store(v, &((f32x4*)ob)[(size_t)px * 64 + lane]);
        }
    }

    // ---------- role 2: channel max/mean pool for images pb0, pb0+1 ----------
    if (pb0 >= 0) {
        const int gg  = blockIdx.x * 16 + (t >> 4);        // 0..32767
        const int sub = t & 15;

        for (int q = gg; q < 2 * IMGPIX; q += NGRP) {
            const int img = q / IMGPIX;
            const int px  = q - img * IMGPIX;
            const int b   = pb0 + img;
            const float* xb  = x + (size_t)b * IMGPIX * C_;
            float2*      pot = pooled + (size_t)b * IMGPIX;

            const f32x4* p4 = (const f32x4*)(xb + (size_t)px * C_);
            float m = -INFINITY, s = 0.0f;
            #pragma unroll
            for (int j = 0; j < 4; ++j) {
                f32x4 v = p4[j * 16 + sub];                // normal load: allocate in L3
                m = fmaxf(m, fmaxf(fmaxf(v.x, v.y), fmaxf(v.z, v.w)));
                s += (v.x + v.y) + (v.z + v.w);
            }
            #pragma unroll
            for (int off = 1; off < 16; off <<= 1) {
                m = fmaxf(m, __shfl_xor(m, off));
                s += __shfl_xor(s, off);
            }
            if (sub == 0) pot[px] = make_float2(m, s * (1.0f / 256.0f));
        }
    }
}

extern "C" void kernel_launch(void* const* d_in, const int* in_sizes, int n_in,
                              void* d_out, int out_size, void* d_ws, size_t ws_size,
                              hipStream_t stream) {
    const float* x  = (const float*)d_in[0];
    const float* cw = (const float*)d_in[1];
    const float* cb = (const float*)d_in[2];
    float* out      = (float*)d_out;
    float2* pooled  = (float2*)d_ws;        // 16*50176*8 B = 6.4 MB

    for (int d = 0; d <= 8; ++d) {
        const int mb0 = (d >= 1) ? 2 * (d - 1) : -1;   // mul images (-1 = none)
        const int pb0 = (d < 8) ? 2 * d : -1;          // pool images (-1 = none)
        step_kernel<<<NBLK, 256, 0, stream>>>(x, cw, cb, out, pooled, mb0, pb0);
    }
}

// Round 8
// 412.181 us; speedup vs baseline: 1.0253x; 1.0134x over previous
//
#include <hip/hip_runtime.h>
#include <math.h>

// SpatialAttention: x[16,224,224,256] f32 (NHWC)
//   max/mean over C -> [B,H,W,2] -> conv7x7(2->1, SAME) -> sigmoid -> x * attn
//
// Pipelined multi-dispatch, 2 images per step (9 dispatches):
//   dispatch d = mul(images 2d-2,2d-1) + pool(images 2d,2d+1).
// Dispatch boundary = CP-level device barrier; mul's x re-read is served by
// Infinity Cache. Measured: mid-dispatches run at ~6.5 TB/s CU-side — the
// fabric ceiling; L3 hits price like HBM, so 2.47 GB total traffic is the
// structural floor (~386 us at 6.4 TB/s).
// R8: alternate role order by block parity so HBM-reads (pool), L3-reads and
// writes (mul) co-issue throughout the dispatch instead of phase-skewing.
#define B_ 16
#define H_ 224
#define W_ 224
#define C_ 256
#define IMGPIX (H_*W_)      // 50176
#define NBLK 2048           // 8 blocks/CU * 256 CU; 32 waves/CU
#define NWAVE (NBLK*4)      // 8192
#define NGRP  (NBLK*16)     // 32768 16-lane groups

typedef float f32x4 __attribute__((ext_vector_type(4)));

__device__ __forceinline__ void mul_role(const float* __restrict__ x,
                                         const float* __restrict__ cw,
                                         const float* __restrict__ cb,
                                         float* __restrict__ out,
                                         const float2* __restrict__ pooled,
                                         int mb0, int t) {
    const int lane = t & 63;
    float wm = 0.0f, wa = 0.0f;
    if (lane < 49) { wm = cw[lane * 2]; wa = cw[lane * 2 + 1]; }
    const float bias = cb[0];
    const int kh = lane / 7 - 3;
    const int kw = lane % 7 - 3;
    const int gw = blockIdx.x * 4 + (t >> 6);          // 0..8191

    for (int q = gw; q < 2 * IMGPIX; q += NWAVE) {
        const int img = q / IMGPIX;                    // 0 or 1
        const int px  = q - img * IMGPIX;
        const int b   = mb0 + img;
        const float*  xb    = x   + (size_t)b * IMGPIX * C_;
        float*        ob    = out + (size_t)b * IMGPIX * C_;
        const float2* pbase = pooled + (size_t)b * IMGPIX;

        const int h = px / W_, w = px % W_;
        float acc = 0.0f;
        if (lane < 49) {
            const int hh = h + kh, ww = w + kw;
            if (hh >= 0 && hh < H_ && ww >= 0 && ww < W_) {
                const float2 pv = pbase[hh * W_ + ww];
                acc = fmaf(pv.x, wm, pv.y * wa);
            }
        }
        #pragma unroll
        for (int off = 1; off < 64; off <<= 1) acc += __shfl_xor(acc, off);
        const float attn = 1.0f / (1.0f + expf(-(acc + bias)));

        f32x4 v = ((const f32x4*)(xb + (size_t)px * C_))[lane];   // L3 hit
        v.x *= attn; v.y *= attn; v.z *= attn; v.w *= attn;
        __builtin_nontemporal_store(v, &((f32x4*)ob)[(size_t)px * 64 + lane]);
    }
}

__device__ __forceinline__ void pool_role(const float* __restrict__ x,
                                          float2* __restrict__ pooled,
                                          int pb0, int t) {
    const int gg  = blockIdx.x * 16 + (t >> 4);        // 0..32767
    const int sub = t & 15;

    for (int q = gg; q < 2 * IMGPIX; q += NGRP) {
        const int img = q / IMGPIX;
        const int px  = q - img * IMGPIX;
        const int b   = pb0 + img;
        const float* xb  = x + (size_t)b * IMGPIX * C_;
        float2*      pot = pooled + (size_t)b * IMGPIX;

        const f32x4* p4 = (const f32x4*)(xb + (size_t)px * C_);
        float m = -INFINITY, s = 0.0f;
        #pragma unroll
        for (int j = 0; j < 4; ++j) {
            f32x4 v = p4[j * 16 + sub];                // normal load: allocate in L3
            m = fmaxf(m, fmaxf(fmaxf(v.x, v.y), fmaxf(v.z, v.w)));
            s += (v.x + v.y) + (v.z + v.w);
        }
        #pragma unroll
        for (int off = 1; off < 16; off <<= 1) {
            m = fmaxf(m, __shfl_xor(m, off));
            s += __shfl_xor(s, off);
        }
        if (sub == 0) pot[px] = make_float2(m, s * (1.0f / 256.0f));
    }
}

__global__ __launch_bounds__(256) void step_kernel(const float* __restrict__ x,
                                                   const float* __restrict__ cw,   // [7,7,2,1]
                                                   const float* __restrict__ cb,
                                                   float* __restrict__ out,
                                                   float2* __restrict__ pooled,
                                                   int mb0, int pb0) {
    const int t = threadIdx.x;
    if (blockIdx.x & 1) {
        if (mb0 >= 0) mul_role(x, cw, cb, out, pooled, mb0, t);
        if (pb0 >= 0) pool_role(x, pooled, pb0, t);
    } else {
        if (pb0 >= 0) pool_role(x, pooled, pb0, t);
        if (mb0 >= 0) mul_role(x, cw, cb, out, pooled, mb0, t);
    }
}

extern "C" void kernel_launch(void* const* d_in, const int* in_sizes, int n_in,
                              void* d_out, int out_size, void* d_ws, size_t ws_size,
                              hipStream_t stream) {
    const float* x  = (const float*)d_in[0];
    const float* cw = (const float*)d_in[1];
    const float* cb = (const float*)d_in[2];
    float* out      = (float*)d_out;
    float2* pooled  = (float2*)d_ws;        // 16*50176*8 B = 6.4 MB

    for (int d = 0; d <= 8; ++d) {
        const int mb0 = (d >= 1) ? 2 * (d - 1) : -1;   // mul images (-1 = none)
        const int pb0 = (d < 8) ? 2 * d : -1;          // pool images (-1 = none)
        step_kernel<<<NBLK, 256, 0, stream>>>(x, cw, cb, out, pooled, mb0, pb0);
    }
}